// Round 3
// baseline (177.708 us; speedup 1.0000x reference)
//
#include <hip/hip_runtime.h>

// SparseWindowedAttention: B=1, S=4096, E=768, H=12, hd=64, window=128
// Inputs are fp32 (per reference); output fp32. We convert x/Wqkv/Wo to bf16
// in workspace and run the GEMMs + attention on MFMA bf16 with fp32 accum.
//
// Pipeline:
//   c0..c2: fp32 -> bf16 converts (x, Wqkv, Wo)
//   k1: qkv = x @ Wqkv^T + bqkv   (M=4096,N=2304,K=768) -> bf16 ws
//   k2: windowed attention         -> attn [4096][768] bf16 ws
//   k3: out = attn @ Wo^T + bo     (M=4096,N=768,K=768) -> fp32 d_out

typedef __attribute__((ext_vector_type(8))) short short8;
typedef __attribute__((ext_vector_type(4))) short short4v;
typedef __attribute__((ext_vector_type(4))) float f32x4;

#define S_LEN 4096
#define EMB   768
#define NH    12
#define HD    64
#define QT    64      // queries per attention block
#define WMAX  128
#define NKT   20      // key tiles of 16 covering [q0-128, q0+192)

__device__ __forceinline__ short f2bf(float f) {
    union { unsigned int i; float f; } c;
    c.f = f;
    unsigned int i = c.i;
    unsigned int r = (i + 0x7FFFu + ((i >> 16) & 1u)) >> 16;
    return (short)(unsigned short)r;
}

__global__ __launch_bounds__(256) void f32_to_bf16(
    const float* __restrict__ in, short* __restrict__ out, int n4)
{
    int i = blockIdx.x * 256 + threadIdx.x;
    if (i < n4) {
        float4 v = ((const float4*)in)[i];
        short4v o = { f2bf(v.x), f2bf(v.y), f2bf(v.z), f2bf(v.w) };
        *(short4v*)(out + (size_t)i * 4) = o;
    }
}

// ---------------------------------------------------------------------------
// GEMM: C[m][n] = sum_k A[m][k]*B[n][k] + bias[n].  A:[M][K] B:[N][K] bf16,
// bias fp32. OUT_BF16 selects bf16 (workspace) vs fp32 (d_out) store.
// Block 256 threads (4 waves), tile 128x128, BK=32.
// ---------------------------------------------------------------------------
template <bool OUT_BF16>
__global__ __launch_bounds__(256) void gemm_bt_bias(
    const short* __restrict__ A, const short* __restrict__ B,
    const float* __restrict__ bias, void* __restrict__ Cv,
    int M, int N, int K)
{
    __shared__ short As[128 * 32];
    __shared__ short Bs[128 * 32];

    const int t = threadIdx.x;
    const int w = t >> 6, l = t & 63;
    const int quad = l >> 4, lane16 = l & 15;
    const int m0 = blockIdx.y * 128, n0 = blockIdx.x * 128;
    const int wm = (w >> 1) * 64, wn = (w & 1) * 64;

    f32x4 acc[4][4];
#pragma unroll
    for (int i = 0; i < 4; ++i)
#pragma unroll
        for (int j = 0; j < 4; ++j) acc[i][j] = (f32x4){0.f, 0.f, 0.f, 0.f};

    for (int k0 = 0; k0 < K; k0 += 32) {
#pragma unroll
        for (int i = 0; i < 2; ++i) {
            int c = i * 256 + t;          // chunk id 0..511
            int r = c >> 2, kc = c & 3;   // row in tile, 8-elem col group
            *(short8*)(As + c * 8) =
                *(const short8*)(A + (size_t)(m0 + r) * K + k0 + kc * 8);
            *(short8*)(Bs + c * 8) =
                *(const short8*)(B + (size_t)(n0 + r) * K + k0 + kc * 8);
        }
        __syncthreads();

        short8 af[4], bfr[4];
#pragma unroll
        for (int mt = 0; mt < 4; ++mt)
            af[mt] = *(const short8*)(As + (wm + mt * 16 + lane16) * 32 + quad * 8);
#pragma unroll
        for (int nt = 0; nt < 4; ++nt)
            bfr[nt] = *(const short8*)(Bs + (wn + nt * 16 + lane16) * 32 + quad * 8);
#pragma unroll
        for (int mt = 0; mt < 4; ++mt)
#pragma unroll
            for (int nt = 0; nt < 4; ++nt)
                acc[mt][nt] = __builtin_amdgcn_mfma_f32_16x16x32_bf16(
                    af[mt], bfr[nt], acc[mt][nt], 0, 0, 0);
        __syncthreads();
    }

    // epilogue: D[row=quad*4+r][col=lane16] per 16x16 tile
#pragma unroll
    for (int nt = 0; nt < 4; ++nt) {
        int col = n0 + wn + nt * 16 + lane16;
        float bv = bias[col];
#pragma unroll
        for (int mt = 0; mt < 4; ++mt) {
#pragma unroll
            for (int r = 0; r < 4; ++r) {
                int row = m0 + wm + mt * 16 + quad * 4 + r;
                float v = acc[mt][nt][r] + bv;
                if (OUT_BF16)
                    ((short*)Cv)[(size_t)row * N + col] = f2bf(v);
                else
                    ((float*)Cv)[(size_t)row * N + col] = v;
            }
        }
    }
}

// ---------------------------------------------------------------------------
// Windowed attention. Block = (q-tile of 64, head). 4 waves; wave w owns
// queries [q0+w*16, q0+w*16+16). Fixed key window [q0-128, q0+192), runtime
// mask |i-j|<=W plus bounds. qkv layout: [S][3E], head h cols at h*192 +
// {0:q, 64:k, 128:v}.  bf16 in ws, bf16 out ws.
// ---------------------------------------------------------------------------
__global__ __launch_bounds__(256) void attn_win(
    const short* __restrict__ qkv, const int* __restrict__ wptr,
    short* __restrict__ attn_out)
{
    __shared__ short Vt[HD][328];      // V^T: Vt[d][key]
    __shared__ short Ps[4][16][40];    // per-wave P chunk [16 q][32 keys]

    const int t = threadIdx.x;
    const int w = t >> 6, l = t & 63;
    const int quad = l >> 4, lane16 = l & 15;
    const int h = blockIdx.y;
    const int q0 = blockIdx.x * QT;
    const int W = *wptr;
    const int kbase = q0 - WMAX;

    // stage V transposed: Vt[d][kk] = V[kbase+kk][d]
    for (int c = t; c < 320 * 8; c += 256) {
        int kk = c >> 3;
        int dc = c & 7;
        int key = kbase + kk;
        int idx = min(max(key, 0), S_LEN - 1);
        short8 v = *(const short8*)(qkv + (size_t)idx * 2304 + h * 192 + 128 + dc * 8);
#pragma unroll
        for (int j = 0; j < 8; ++j)
            Vt[dc * 8 + j][kk] = v[j];
    }
    __syncthreads();

    // Q fragments (A-operand: m=lane16, k=quad*8+j), 2 K-halves of hd=64
    const int qrow = q0 + w * 16 + lane16;
    const short* qp = qkv + (size_t)qrow * 2304 + h * 192;
    short8 aq0 = *(const short8*)(qp + quad * 8);
    short8 aq1 = *(const short8*)(qp + 32 + quad * 8);

    // scores: 20 key-tiles of 16; K-frags streamed from global (L2-hot)
    f32x4 sc[NKT];
#pragma unroll
    for (int kt = 0; kt < NKT; ++kt) {
        int key = kbase + kt * 16 + lane16;
        int idx = min(max(key, 0), S_LEN - 1);
        const short* kp = qkv + (size_t)idx * 2304 + h * 192 + 64;
        short8 b0 = *(const short8*)(kp + quad * 8);
        short8 b1 = *(const short8*)(kp + 32 + quad * 8);
        f32x4 a = (f32x4){0.f, 0.f, 0.f, 0.f};
        a = __builtin_amdgcn_mfma_f32_16x16x32_bf16(aq0, b0, a, 0, 0, 0);
        a = __builtin_amdgcn_mfma_f32_16x16x32_bf16(aq1, b1, a, 0, 0, 0);
        sc[kt] = a;
    }

    // mask + scale, row max (C layout: row=quad*4+r, col=lane16)
    const float scale = 0.125f;  // 1/sqrt(64)
    float mrow[4], lsum[4];
#pragma unroll
    for (int r = 0; r < 4; ++r) mrow[r] = -1e30f;
#pragma unroll
    for (int kt = 0; kt < NKT; ++kt) {
        int key = kbase + kt * 16 + lane16;
#pragma unroll
        for (int r = 0; r < 4; ++r) {
            int qi = q0 + w * 16 + quad * 4 + r;
            int d = qi - key;
            int ad = d < 0 ? -d : d;
            bool valid = (key >= 0) && (key < S_LEN) && (ad <= W);
            float s = valid ? sc[kt][r] * scale : -1e30f;
            sc[kt][r] = s;
            mrow[r] = fmaxf(mrow[r], s);
        }
    }
#pragma unroll
    for (int r = 0; r < 4; ++r) {
#pragma unroll
        for (int off = 1; off < 16; off <<= 1)
            mrow[r] = fmaxf(mrow[r], __shfl_xor(mrow[r], off, 64));
    }
    // exp + row sum
#pragma unroll
    for (int r = 0; r < 4; ++r) lsum[r] = 0.f;
#pragma unroll
    for (int kt = 0; kt < NKT; ++kt) {
#pragma unroll
        for (int r = 0; r < 4; ++r) {
            float p = __expf(sc[kt][r] - mrow[r]);
            sc[kt][r] = p;
            lsum[r] += p;
        }
    }
#pragma unroll
    for (int r = 0; r < 4; ++r) {
#pragma unroll
        for (int off = 1; off < 16; off <<= 1)
            lsum[r] += __shfl_xor(lsum[r], off, 64);
        lsum[r] = fmaxf(lsum[r], 1e-30f);
    }

    // PV: 10 chunks of 32 keys; C-layout -> A-layout via LDS, barrier-bracketed
    f32x4 outacc[4];
#pragma unroll
    for (int nt = 0; nt < 4; ++nt) outacc[nt] = (f32x4){0.f, 0.f, 0.f, 0.f};

#pragma unroll
    for (int chunk = 0; chunk < 10; ++chunk) {
#pragma unroll
        for (int half = 0; half < 2; ++half) {
            int kt = chunk * 2 + half;
#pragma unroll
            for (int r = 0; r < 4; ++r)
                Ps[w][quad * 4 + r][half * 16 + lane16] = f2bf(sc[kt][r]);
        }
        __syncthreads();
        short8 ap = *(const short8*)(&Ps[w][lane16][quad * 8]);
#pragma unroll
        for (int nt = 0; nt < 4; ++nt) {
            short8 bv = *(const short8*)(&Vt[nt * 16 + lane16][chunk * 32 + quad * 8]);
            outacc[nt] = __builtin_amdgcn_mfma_f32_16x16x32_bf16(ap, bv, outacc[nt], 0, 0, 0);
        }
        __syncthreads();
    }

    // normalize + store
#pragma unroll
    for (int nt = 0; nt < 4; ++nt) {
        int col = h * HD + nt * 16 + lane16;
#pragma unroll
        for (int r = 0; r < 4; ++r) {
            int qi = q0 + w * 16 + quad * 4 + r;
            attn_out[(size_t)qi * EMB + col] = f2bf(outacc[nt][r] / lsum[r]);
        }
    }
}

extern "C" void kernel_launch(void* const* d_in, const int* in_sizes, int n_in,
                              void* d_out, int out_size, void* d_ws, size_t ws_size,
                              hipStream_t stream) {
    const float* x    = (const float*)d_in[0];   // [4096][768] fp32
    const float* Wqkv = (const float*)d_in[1];   // [2304][768] fp32
    const float* bqkv = (const float*)d_in[2];   // [2304] fp32
    const float* Wo   = (const float*)d_in[3];   // [768][768] fp32
    const float* bo   = (const float*)d_in[4];   // [768] fp32
    const int*   wptr = (const int*)d_in[5];     // window_size

    float* out = (float*)d_out;                  // [4096][768] fp32

    // workspace layout (bf16 shorts), all 16B-aligned offsets
    short* xb    = (short*)d_ws;                       //  4096*768
    short* wqkvb = xb    + (size_t)S_LEN * EMB;        //  2304*768
    short* wob   = wqkvb + (size_t)3 * EMB * EMB;      //   768*768
    short* qkv   = wob   + (size_t)EMB * EMB;          //  4096*2304
    short* attn  = qkv   + (size_t)S_LEN * 3 * EMB;    //  4096*768

    dim3 blk(256);
    {
        int n4 = S_LEN * EMB / 4;
        f32_to_bf16<<<dim3((n4 + 255) / 256), blk, 0, stream>>>(x, xb, n4);
        n4 = 3 * EMB * EMB / 4;
        f32_to_bf16<<<dim3((n4 + 255) / 256), blk, 0, stream>>>(Wqkv, wqkvb, n4);
        n4 = EMB * EMB / 4;
        f32_to_bf16<<<dim3((n4 + 255) / 256), blk, 0, stream>>>(Wo, wob, n4);
    }

    gemm_bt_bias<true><<<dim3(2304 / 128, S_LEN / 128), blk, 0, stream>>>(
        xb, wqkvb, bqkv, qkv, S_LEN, 2304, EMB);
    attn_win<<<dim3(S_LEN / QT, NH), blk, 0, stream>>>(qkv, wptr, attn);
    gemm_bt_bias<false><<<dim3(EMB / 128, S_LEN / 128), blk, 0, stream>>>(
        attn, wob, bo, out, S_LEN, EMB, EMB);
}

// Round 5
// 170.343 us; speedup vs baseline: 1.0432x; 1.0432x over previous
//
#include <hip/hip_runtime.h>

// SparseWindowedAttention: B=1, S=4096, E=768, H=12, hd=64, window=128
// Inputs fp32 (converted to bf16 in ws), output fp32. MFMA bf16, fp32 accum.
//
//   c0: fused fp32->bf16 convert (x, Wqkv, Wo)
//   k1: qkv = x @ Wqkv^T + bqkv   (M=4096,N=2304,K=768) -> bf16 ws   [global_load_lds]
//   k2: windowed attention (S^T trick: zero-barrier PV)  -> bf16 ws
//   k3: out = attn @ Wo^T + bo    (M=4096,N=768,K=768)  -> fp32 d_out

typedef __attribute__((ext_vector_type(8))) short short8;
typedef __attribute__((ext_vector_type(4))) short short4v;
typedef __attribute__((ext_vector_type(4))) float f32x4;

#define S_LEN 4096
#define EMB   768
#define NH    12
#define HD    64
#define QT    64      // queries per attention block (16 per wave)
#define WMAX  128
#define NKT   20      // key tiles of 16 covering [q0-128, q0+192)
#define VSTR  332     // Vt row stride in shorts: 664B, 8B-aligned, 166dw%32=6 -> min-conflict b64 reads

// Device pass: _1k builtin exists on gfx950 (R4 device compile succeeded).
// Host pass: x86 __has_builtin is false for amdgcn MFMA _1k -> give the host
// parser a benign, type-correct expansion; host never executes device code.
#if defined(__HIP_DEVICE_COMPILE__)
#define MFMA16(a, b, c) __builtin_amdgcn_mfma_f32_16x16x16bf16_1k(a, b, c, 0, 0, 0)
#else
#define MFMA16(a, b, c) (c)
#endif

__device__ __forceinline__ short f2bf(float f) {
    union { unsigned int i; float f; } c;
    c.f = f;
    unsigned int i = c.i;
    unsigned int r = (i + 0x7FFFu + ((i >> 16) & 1u)) >> 16;
    return (short)(unsigned short)r;
}

// fused fp32->bf16: segments [x | Wqkv | Wo], one float4 per thread
#define NX4  (S_LEN * EMB / 4)
#define NW4  (3 * EMB * EMB / 4)
#define NO4  (EMB * EMB / 4)
__global__ __launch_bounds__(256) void convert_all(
    const float* __restrict__ x, const float* __restrict__ wqkv,
    const float* __restrict__ wo, short* __restrict__ xb,
    short* __restrict__ wqkvb, short* __restrict__ wob)
{
    int i = blockIdx.x * 256 + threadIdx.x;
    const float* src; short* dst; int off;
    if (i < NX4)            { src = x;    dst = xb;    off = i; }
    else if (i < NX4 + NW4) { src = wqkv; dst = wqkvb; off = i - NX4; }
    else                    { src = wo;   dst = wob;   off = i - NX4 - NW4; }
    float4 v = ((const float4*)src)[off];
    short4v o = { f2bf(v.x), f2bf(v.y), f2bf(v.z), f2bf(v.w) };
    *(short4v*)(dst + (size_t)off * 4) = o;
}

// ---------------------------------------------------------------------------
// GEMM: C[m][n] = sum_k A[m][k]*B[n][k] + bias[n].  A:[M][K] B:[N][K] bf16,
// bias fp32. OUT_BF16 selects bf16 (ws) vs fp32 (d_out) store.
// 256 threads (4 waves), tile 128x128, BK=32, async global->LDS staging.
// ---------------------------------------------------------------------------
template <bool OUT_BF16>
__global__ __launch_bounds__(256) void gemm_bt_bias(
    const short* __restrict__ A, const short* __restrict__ B,
    const float* __restrict__ bias, void* __restrict__ Cv,
    int M, int N, int K)
{
    __shared__ __align__(16) short As[128 * 32];
    __shared__ __align__(16) short Bs[128 * 32];

    const int t = threadIdx.x;
    const int w = t >> 6, l = t & 63;
    const int quad = l >> 4, lane16 = l & 15;
    const int m0 = blockIdx.y * 128, n0 = blockIdx.x * 128;
    const int wm = (w >> 1) * 64, wn = (w & 1) * 64;

    f32x4 acc[4][4];
#pragma unroll
    for (int i = 0; i < 4; ++i)
#pragma unroll
        for (int j = 0; j < 4; ++j) acc[i][j] = (f32x4){0.f, 0.f, 0.f, 0.f};

    for (int k0 = 0; k0 < K; k0 += 32) {
        // async global->LDS, 16B/lane: lds dst = wave-uniform base + lane*16
#pragma unroll
        for (int i = 0; i < 2; ++i) {
            int c = i * 256 + t;          // chunk id 0..511
            int r = c >> 2, kc = c & 3;   // row in tile, 8-elem col group
#if defined(__HIP_DEVICE_COMPILE__) && __has_builtin(__builtin_amdgcn_global_load_lds)
            __builtin_amdgcn_global_load_lds(
                (const __attribute__((address_space(1))) void*)(A + (size_t)(m0 + r) * K + k0 + kc * 8),
                (__attribute__((address_space(3))) void*)(As + c * 8), 16, 0, 0);
            __builtin_amdgcn_global_load_lds(
                (const __attribute__((address_space(1))) void*)(B + (size_t)(n0 + r) * K + k0 + kc * 8),
                (__attribute__((address_space(3))) void*)(Bs + c * 8), 16, 0, 0);
#else
            *(short8*)(As + c * 8) = *(const short8*)(A + (size_t)(m0 + r) * K + k0 + kc * 8);
            *(short8*)(Bs + c * 8) = *(const short8*)(B + (size_t)(n0 + r) * K + k0 + kc * 8);
#endif
        }
        __syncthreads();   // drains vmcnt (incl. lds-DMA) + lgkm

        short8 af[4], bfr[4];
#pragma unroll
        for (int mt = 0; mt < 4; ++mt)
            af[mt] = *(const short8*)(As + (wm + mt * 16 + lane16) * 32 + quad * 8);
#pragma unroll
        for (int nt = 0; nt < 4; ++nt)
            bfr[nt] = *(const short8*)(Bs + (wn + nt * 16 + lane16) * 32 + quad * 8);
#pragma unroll
        for (int mt = 0; mt < 4; ++mt)
#pragma unroll
            for (int nt = 0; nt < 4; ++nt)
                acc[mt][nt] = __builtin_amdgcn_mfma_f32_16x16x32_bf16(
                    af[mt], bfr[nt], acc[mt][nt], 0, 0, 0);
        __syncthreads();
    }

    // epilogue: D[row=quad*4+r][col=lane16] per 16x16 tile
#pragma unroll
    for (int nt = 0; nt < 4; ++nt) {
        int col = n0 + wn + nt * 16 + lane16;
        float bv = bias[col];
#pragma unroll
        for (int mt = 0; mt < 4; ++mt) {
#pragma unroll
            for (int r = 0; r < 4; ++r) {
                int row = m0 + wm + mt * 16 + quad * 4 + r;
                float v = acc[mt][nt][r] + bv;
                if (OUT_BF16)
                    ((short*)Cv)[(size_t)row * N + col] = f2bf(v);
                else
                    ((float*)Cv)[(size_t)row * N + col] = v;
            }
        }
    }
}

// ---------------------------------------------------------------------------
// Windowed attention, S^T formulation (one barrier total).
// Block = (q-tile of 64, head); wave w owns queries [q0+w*16, q0+w*16+16),
// one query per lane16-column. Key window [q0-128, q0+192).
//   St = K·Q^T via mfma(A=K, B=Q): C-layout row=key(quad*4+r), col=q(lane16).
//   Softmax per column q: per-lane over 80 regs, then shfl_xor 16/32.
//   P (C-layout) IS the B-operand of mfma_16x16x16 (k=quad*4+j) -> no transpose.
//   O^T = V^T·P accumulated per 16-dim tile; V^T staged once in LDS.
// ---------------------------------------------------------------------------
__global__ __launch_bounds__(256) void attn_win(
    const short* __restrict__ qkv, const int* __restrict__ wptr,
    short* __restrict__ attn_out)
{
    __shared__ __align__(16) short Vt[HD][VSTR];   // V^T: Vt[d][key], 42496 B -> 3 blk/CU

    const int t = threadIdx.x;
    const int w = t >> 6, l = t & 63;
    const int quad = l >> 4, lane16 = l & 15;
    const int h = blockIdx.y;
    const int q0 = blockIdx.x * QT;
    const int W = *wptr;
    const int kbase = q0 - WMAX;

    // stage V transposed: Vt[d][kk] = V[kbase+kk][d]
    for (int c = t; c < 320 * 8; c += 256) {
        int kk = c >> 3;
        int dc = c & 7;
        int key = kbase + kk;
        int idx = min(max(key, 0), S_LEN - 1);
        short8 v = *(const short8*)(qkv + (size_t)idx * 2304 + h * 192 + 128 + dc * 8);
#pragma unroll
        for (int j = 0; j < 8; ++j)
            Vt[dc * 8 + j][kk] = v[j];
    }
    __syncthreads();   // the only barrier

    // Q as B-operand: B[n=q=lane16][k=dim=quad*8+j], two 32-dim halves
    const int qi = q0 + w * 16 + lane16;
    const short* qp = qkv + (size_t)qi * 2304 + h * 192;
    short8 bq0 = *(const short8*)(qp + quad * 8);
    short8 bq1 = *(const short8*)(qp + 32 + quad * 8);

    // St[key][q] per 16-key tile; K as A-operand streamed from global (L2-hot)
    f32x4 sc[NKT];
#pragma unroll
    for (int kt = 0; kt < NKT; ++kt) {
        int key = kbase + kt * 16 + lane16;
        int idx = min(max(key, 0), S_LEN - 1);
        const short* kp = qkv + (size_t)idx * 2304 + h * 192 + 64;
        short8 a0 = *(const short8*)(kp + quad * 8);
        short8 a1 = *(const short8*)(kp + 32 + quad * 8);
        f32x4 a = (f32x4){0.f, 0.f, 0.f, 0.f};
        a = __builtin_amdgcn_mfma_f32_16x16x32_bf16(a0, bq0, a, 0, 0, 0);
        a = __builtin_amdgcn_mfma_f32_16x16x32_bf16(a1, bq1, a, 0, 0, 0);
        sc[kt] = a;
    }

    // mask + scale + column(=q) max
    const float scale = 0.125f;  // 1/sqrt(64)
    float m = -1e30f;
#pragma unroll
    for (int kt = 0; kt < NKT; ++kt) {
#pragma unroll
        for (int r = 0; r < 4; ++r) {
            int key = kbase + kt * 16 + quad * 4 + r;
            int d = qi - key;
            int ad = d < 0 ? -d : d;
            bool valid = (key >= 0) && (key < S_LEN) && (ad <= W);
            float s = valid ? sc[kt][r] * scale : -1e30f;
            sc[kt][r] = s;
            m = fmaxf(m, s);
        }
    }
    m = fmaxf(m, __shfl_xor(m, 16, 64));
    m = fmaxf(m, __shfl_xor(m, 32, 64));

    float lsum = 0.f;
#pragma unroll
    for (int kt = 0; kt < NKT; ++kt) {
#pragma unroll
        for (int r = 0; r < 4; ++r) {
            float p = __expf(sc[kt][r] - m);
            sc[kt][r] = p;
            lsum += p;
        }
    }
    lsum += __shfl_xor(lsum, 16, 64);
    lsum += __shfl_xor(lsum, 32, 64);
    const float rl = 1.f / fmaxf(lsum, 1e-30f);

    // PV: O^T[d][q] += V^T[d][k] * P[q][k]; P C-layout == B-frag of 16x16x16
    f32x4 oacc[4];
#pragma unroll
    for (int nt = 0; nt < 4; ++nt) oacc[nt] = (f32x4){0.f, 0.f, 0.f, 0.f};

#pragma unroll
    for (int kt = 0; kt < NKT; ++kt) {
        short4v pb = { f2bf(sc[kt][0]), f2bf(sc[kt][1]),
                       f2bf(sc[kt][2]), f2bf(sc[kt][3]) };
#pragma unroll
        for (int nt = 0; nt < 4; ++nt) {
            short4v va = *(const short4v*)(&Vt[nt * 16 + lane16][kt * 16 + quad * 4]);
            oacc[nt] = MFMA16(va, pb, oacc[nt]);
        }
    }

    // normalize + store: O^T C-layout row=d=quad*4+r, col=q=lane16 -> 8B stores
#pragma unroll
    for (int nt = 0; nt < 4; ++nt) {
        short4v ob = { f2bf(oacc[nt][0] * rl), f2bf(oacc[nt][1] * rl),
                       f2bf(oacc[nt][2] * rl), f2bf(oacc[nt][3] * rl) };
        *(short4v*)(attn_out + (size_t)qi * EMB + h * HD + nt * 16 + quad * 4) = ob;
    }
}

extern "C" void kernel_launch(void* const* d_in, const int* in_sizes, int n_in,
                              void* d_out, int out_size, void* d_ws, size_t ws_size,
                              hipStream_t stream) {
    const float* x    = (const float*)d_in[0];   // [4096][768] fp32
    const float* Wqkv = (const float*)d_in[1];   // [2304][768] fp32
    const float* bqkv = (const float*)d_in[2];   // [2304] fp32
    const float* Wo   = (const float*)d_in[3];   // [768][768] fp32
    const float* bo   = (const float*)d_in[4];   // [768] fp32
    const int*   wptr = (const int*)d_in[5];     // window_size

    float* out = (float*)d_out;                  // [4096][768] fp32

    // workspace (bf16 shorts), 16B-aligned offsets
    short* xb    = (short*)d_ws;                       //  4096*768
    short* wqkvb = xb    + (size_t)S_LEN * EMB;        //  2304*768
    short* wob   = wqkvb + (size_t)3 * EMB * EMB;      //   768*768
    short* qkv   = wob   + (size_t)EMB * EMB;          //  4096*2304
    short* attn  = qkv   + (size_t)S_LEN * 3 * EMB;    //  4096*768

    dim3 blk(256);
    convert_all<<<dim3((NX4 + NW4 + NO4) / 256), blk, 0, stream>>>(
        x, Wqkv, Wo, xb, wqkvb, wob);
    gemm_bt_bias<true><<<dim3(2304 / 128, S_LEN / 128), blk, 0, stream>>>(
        xb, wqkvb, bqkv, qkv, S_LEN, 2304, EMB);
    attn_win<<<dim3(S_LEN / QT, NH), blk, 0, stream>>>(qkv, wptr, attn);
    gemm_bt_bias<false><<<dim3(EMB / 128, S_LEN / 128), blk, 0, stream>>>(
        attn, wob, bo, out, S_LEN, EMB, EMB);
}